// Round 10
// baseline (383.915 us; speedup 1.0000x reference)
//
#include <hip/hip_runtime.h>
#include <hip/hip_fp16.h>
#include <math.h>

#define IN_CH 128
#define HEADS 8
#define HID 16
#define OUT_CH 16
#define NEG 0.2f
#define NPB 256          // nodes per bucket (>>8)
#define MAXBUCK 400
#define AST 136          // LDS k-stride in halfs (128 + 8 pad)

__device__ __forceinline__ float lrelu(float x){ return x > 0.f ? x : NEG * x; }

typedef _Float16 half8 __attribute__((ext_vector_type(8)));
typedef float    f32x4 __attribute__((ext_vector_type(4)));

// ---------------- bucketed CSR build ----------------
__global__ __launch_bounds__(256) void k_bhist(const int* __restrict__ tgt, int E, int nbuck, int epb,
                                               int* __restrict__ bcnt){
    __shared__ int hist[MAXBUCK];
    int tid = threadIdx.x;
    for (int i = tid; i < nbuck; i += 256) hist[i] = 0;
    __syncthreads();
    int start = blockIdx.x * epb, end = min(start + epb, E);
    for (int e = start + tid; e < end; e += 256) atomicAdd(&hist[tgt[e] >> 8], 1);
    __syncthreads();
    for (int i = tid; i < nbuck; i += 256) if (hist[i]) atomicAdd(&bcnt[i], hist[i]);
}

__global__ void k_bscan(const int* __restrict__ bcnt, int nbuck, int E,
                        int* __restrict__ boffs, int* __restrict__ bcur){
    __shared__ int s[512];
    int t = threadIdx.x;
    int v = (t < nbuck) ? bcnt[t] : 0;
    int orig = v;
    s[t] = v; __syncthreads();
    for (int off = 1; off < 512; off <<= 1){
        int u = (t >= off) ? s[t - off] : 0;
        __syncthreads();
        v += u; s[t] = v; __syncthreads();
    }
    if (t < nbuck){ boffs[t] = v - orig; bcur[t] = v - orig; }
    if (t == 0) boffs[nbuck] = E;
}

__global__ __launch_bounds__(256) void k_bscatter(const int* __restrict__ ei, int E, int nbuck, int epb,
                                                  int* __restrict__ bcur, int2* __restrict__ ebuck){
    __shared__ int hist[MAXBUCK];
    __shared__ int base[MAXBUCK];
    int tid = threadIdx.x;
    for (int i = tid; i < nbuck; i += 256) hist[i] = 0;
    __syncthreads();
    int start = blockIdx.x * epb, end = min(start + epb, E);
    for (int e = start + tid; e < end; e += 256) atomicAdd(&hist[ei[E + e] >> 8], 1);
    __syncthreads();
    for (int i = tid; i < nbuck; i += 256){
        base[i] = hist[i] ? atomicAdd(&bcur[i], hist[i]) : 0;
        hist[i] = 0;
    }
    __syncthreads();
    for (int e = start + tid; e < end; e += 256){
        int s = ei[e], t = ei[E + e];
        int b = t >> 8;
        int r = atomicAdd(&hist[b], 1);
        ebuck[base[b] + r] = make_int2(s, t);
    }
}

__global__ __launch_bounds__(256) void k_csr(const int2* __restrict__ ebuck, const int* __restrict__ boffs,
                                             int N, int E,
                                             int* __restrict__ offs, int* __restrict__ esrc){
    __shared__ int cnt[256];
    __shared__ int sscan[256];
    __shared__ int wcur[256];
    int b = blockIdx.x;
    int tid = threadIdx.x;
    int n0 = b * 256;
    int nn = min(256, N - n0);
    cnt[tid] = (tid < nn) ? 1 : 0;
    __syncthreads();
    int e0 = boffs[b], e1 = boffs[b + 1];
    for (int e = e0 + tid; e < e1; e += 256) atomicAdd(&cnt[ebuck[e].y & 255], 1);
    __syncthreads();
    int v = cnt[tid], orig = v;
    sscan[tid] = v; __syncthreads();
    for (int off = 1; off < 256; off <<= 1){
        int u = (tid >= off) ? sscan[tid - off] : 0;
        __syncthreads();
        v += u; sscan[tid] = v; __syncthreads();
    }
    int excl = v - orig;
    int gbase = e0 + n0;
    if (tid < nn){
        offs[n0 + tid] = gbase + excl;
        esrc[gbase + excl] = n0 + tid;
    }
    wcur[tid] = excl + 1;
    __syncthreads();
    for (int e = e0 + tid; e < e1; e += 256){
        int2 p = ebuck[e];
        int r = atomicAdd(&wcur[p.y & 255], 1);
        esrc[gbase + r] = p.x;
    }
    if (b == 0 && tid == 0) offs[N] = E + N;
}

// ---------------- GEMM1 (MFMA fp16): h1 = x @ W1 -> fp16 [N][128] ----------------
__global__ __launch_bounds__(256) void k_gemm1(const float* __restrict__ x, const float* __restrict__ W1,
                                               __half* __restrict__ h1, int N){
    __shared__ _Float16 sA[64*AST];    // 17.4 KB
    __shared__ _Float16 sB[128*AST];   // 34.8 KB
    int tid = threadIdx.x;
    for (int i = tid; i < 128*128; i += 256){
        int k = i >> 7, c = i & 127;
        sB[c*AST + k] = (_Float16)W1[i];
    }
    int row0 = blockIdx.x * 64;
    #pragma unroll
    for (int i = 0; i < 8; ++i){
        int q = i*256 + tid;
        int r = q >> 5, seg = q & 31;
        float4 v = make_float4(0.f,0.f,0.f,0.f);
        if (row0 + r < N) v = *(const float4*)(x + (size_t)(row0+r)*128 + seg*4);
        _Float16* dst = &sA[r*AST + seg*4];
        dst[0]=(_Float16)v.x; dst[1]=(_Float16)v.y; dst[2]=(_Float16)v.z; dst[3]=(_Float16)v.w;
    }
    __syncthreads();
    int wave = tid >> 6, lane = tid & 63;
    int m = lane & 15, quad = lane >> 4;
    int rbase = wave * 16;
    f32x4 acc[8] = {};
    #pragma unroll
    for (int kc = 0; kc < 4; ++kc){
        int kb = kc*32 + quad*8;
        half8 a = *(half8*)(&sA[(rbase + m)*AST + kb]);
        #pragma unroll
        for (int t = 0; t < 8; ++t){
            half8 b = *(half8*)(&sB[(t*16 + m)*AST + kb]);
            acc[t] = __builtin_amdgcn_mfma_f32_16x16x32_f16(a, b, acc[t], 0, 0, 0);
        }
    }
    #pragma unroll
    for (int t = 0; t < 8; ++t){
        #pragma unroll
        for (int j = 0; j < 4; ++j){
            int r = row0 + rbase + quad*4 + j;
            if (r < N) h1[(size_t)r*128 + t*16 + m] = __float2half(acc[t][j]);
        }
    }
}

// ---------------- attention logits, layer 1 ----------------
struct H8 { __half2 v[8]; };

__global__ void k_alpha1(const __half2* __restrict__ h1h, const float* __restrict__ asrc, const float* __restrict__ adst,
                         float* __restrict__ as1, float* __restrict__ ad1, int N){
    int idx = blockIdx.x*blockDim.x + threadIdx.x;
    if (idx >= N*HEADS) return;
    int h = idx & 7;
    int n = idx >> 3;
    H8 blk = *(const H8*)(h1h + (size_t)n*64 + h*8);
    const float2* sp = (const float2*)(asrc + h*16);
    const float2* dp = (const float2*)(adst + h*16);
    float ss = 0.f, dd = 0.f;
    #pragma unroll
    for (int j = 0; j < 8; ++j){
        float2 v = __half22float2(blk.v[j]);
        float2 a = sp[j], b = dp[j];
        ss += v.x*a.x + v.y*a.y;
        dd += v.x*b.x + v.y*b.y;
    }
    as1[idx] = ss; ad1[idx] = dd;
}

// ---------------- layer-1 aggregation: LDS-mediated weight dedup ----------------
// one wave per node. Per 8-edge chunk:
//   weight pass: lane l computes ONE w for (slot=l>>3, head=l&7) -> sW[wv][slot][head];
//                lane with (l&7)==0 stores src -> sS[wv][slot].
//   channel pass: lane l owns ch 2l,2l+1 (head l>>3); reads w (8-lane LDS broadcast)
//                 and s, gathers h1 row, 2 FMA + den. Intra-wave lockstep => no barrier.
__global__ __launch_bounds__(256) void k_agg1(const __half2* __restrict__ h1h, const float* __restrict__ as1,
                                              const float* __restrict__ ad1,
                                              const int* __restrict__ offs, const int* __restrict__ esrc,
                                              const float* __restrict__ b1, __half2* __restrict__ hl2h, int N){
    __shared__ float sW[4][8][8];
    __shared__ int   sS[4][8];
    int wv = threadIdx.x >> 6;
    int n = blockIdx.x*4 + wv;
    if (n >= N) return;
    int l = threadIdx.x & 63;
    int slot = l >> 3, hw = l & 7;
    int h = l >> 3;
    float ad_w = ad1[n*8 + hw];
    int e0 = offs[n], e1 = offs[n+1];

    float2 acc = make_float2(0.f,0.f);
    float den = 0.f;
    for (int g = e0; g < e1; g += 8){
        int es = g + slot;
        float w = 0.f; int s = 0;
        if (es < e1){
            s = esrc[es];
            w = __expf(lrelu(as1[s*8 + hw] + ad_w));
        }
        sW[wv][slot][hw] = w;
        if (hw == 0) sS[wv][slot] = s;
        #pragma unroll
        for (int j = 0; j < 8; ++j){
            if (g + j >= e1) break;          // wave-uniform
            float wj = sW[wv][j][h];
            int   sj = sS[wv][j];
            float2 hv = __half22float2(h1h[(size_t)sj*64 + l]);
            den += wj;
            acc.x += wj*hv.x; acc.y += wj*hv.y;
        }
    }
    float rd = 1.f / (den + 1e-16f);
    float2 bb = ((const float2*)b1)[l];
    float vx = acc.x*rd + bb.x;
    float vy = acc.y*rd + bb.y;
    vx = vx > 0.f ? vx : expm1f(vx);
    vy = vy > 0.f ? vy : expm1f(vy);
    hl2h[(size_t)n*64 + l] = __floats2half2_rn(vx, vy);
}

// ---------------- GEMM2: h2 = hl2 @ W2 + fused alpha2 ----------------
#define FMA4(acc, a, b) { acc.x += (a)*(b).x; acc.y += (a)*(b).y; acc.z += (a)*(b).z; acc.w += (a)*(b).w; }

__global__ __launch_bounds__(256) void k_gemm2(const __half2* __restrict__ hl2h, const float* __restrict__ W2,
                                               const float* __restrict__ asrc2, const float* __restrict__ adst2,
                                               float* __restrict__ h2, float* __restrict__ as2, float* __restrict__ ad2,
                                               int N){
    __shared__ float sX[64*132];
    __shared__ float sW2[128*16];
    int tid = threadIdx.x;
    for (int i = tid; i < 128*16; i += 256) sW2[i] = W2[i];
    int row0 = blockIdx.x * 64;
    #pragma unroll
    for (int i = 0; i < 4; ++i){
        int q = i*256 + tid;
        int r = q >> 4, seg = q & 15;
        float4 raw = make_float4(0.f,0.f,0.f,0.f);
        if (row0 + r < N) raw = ((const float4*)(hl2h + (size_t)(row0+r)*64))[seg];
        const __half2* hp = (const __half2*)&raw;
        float* dst = &sX[r*132 + seg*8];
        #pragma unroll
        for (int j = 0; j < 4; ++j){
            float2 f = __half22float2(hp[j]);
            dst[2*j] = f.x; dst[2*j+1] = f.y;
        }
    }
    __syncthreads();
    int nd = tid >> 2;
    int cq = tid & 3, c0 = cq*4;
    int n = row0 + nd;
    float4 acc = make_float4(0.f,0.f,0.f,0.f);
    #pragma unroll 4
    for (int k4 = 0; k4 < 32; ++k4){
        float4 a  = *(const float4*)(&sX[nd*132 + k4*4]);
        float4 w0 = *(const float4*)(&sW2[(k4*4+0)*16 + c0]);
        float4 w1 = *(const float4*)(&sW2[(k4*4+1)*16 + c0]);
        float4 w2 = *(const float4*)(&sW2[(k4*4+2)*16 + c0]);
        float4 w3 = *(const float4*)(&sW2[(k4*4+3)*16 + c0]);
        FMA4(acc, a.x, w0); FMA4(acc, a.y, w1); FMA4(acc, a.z, w2); FMA4(acc, a.w, w3);
    }
    float ps = acc.x*asrc2[c0] + acc.y*asrc2[c0+1] + acc.z*asrc2[c0+2] + acc.w*asrc2[c0+3];
    float pd = acc.x*adst2[c0] + acc.y*adst2[c0+1] + acc.z*adst2[c0+2] + acc.w*adst2[c0+3];
    ps += __shfl_xor(ps, 1); ps += __shfl_xor(ps, 2);
    pd += __shfl_xor(pd, 1); pd += __shfl_xor(pd, 2);
    if (n < N){
        *(float4*)(&h2[(size_t)n*16 + c0]) = acc;
        if (cq == 0){ as2[n] = ps; ad2[n] = pd; }
    }
}

// ---------------- layer-2 aggregation: LDS-mediated weight dedup -> out ----------------
// one wave per node. Per 64-edge chunk: lane l computes w for edge g+l -> sW/sS;
// channel pass: lanes = 4 edge-slots x 16 ch, slot eo walks j=eo,eo+4,...; final
// shfl reduce over the two slot bits.
__global__ __launch_bounds__(256) void k_agg2(const float* __restrict__ h2, const float* __restrict__ as2v,
                                              const float* __restrict__ ad2v,
                                              const int* __restrict__ offs, const int* __restrict__ esrc,
                                              const float* __restrict__ b2, float* __restrict__ out, int N){
    __shared__ float sW[4][64];
    __shared__ int   sS[4][64];
    int wv = threadIdx.x >> 6;
    int n = blockIdx.x*4 + wv;
    if (n >= N) return;
    int l = threadIdx.x & 63;
    int e0 = offs[n], e1 = offs[n+1];
    float ad = ad2v[n];
    int eo = l >> 4, c = l & 15;
    float acc = 0.f, den = 0.f;
    for (int g = e0; g < e1; g += 64){
        int es = g + l;
        float w = 0.f; int s = 0;
        if (es < e1){
            s = esrc[es];
            w = __expf(lrelu(as2v[s] + ad));
        }
        sW[wv][l] = w; sS[wv][l] = s;
        int m = e1 - g; if (m > 64) m = 64;
        int j = eo;
        for (; j + 4 < m; j += 8){
            float w0 = sW[wv][j],   w1 = sW[wv][j+4];
            int   s0 = sS[wv][j],   s1 = sS[wv][j+4];
            den += w0 + w1;
            acc += w0 * h2[(size_t)s0*16 + c];
            acc += w1 * h2[(size_t)s1*16 + c];
        }
        if (j < m){
            float w0 = sW[wv][j];
            int   s0 = sS[wv][j];
            den += w0;
            acc += w0 * h2[(size_t)s0*16 + c];
        }
    }
    acc += __shfl_xor(acc, 16); den += __shfl_xor(den, 16);
    acc += __shfl_xor(acc, 32); den += __shfl_xor(den, 32);
    if (eo == 0) out[(size_t)n*16 + c] = acc / (den + 1e-16f) + b2[c];
}

extern "C" void kernel_launch(void* const* d_in, const int* in_sizes, int n_in,
                              void* d_out, int out_size, void* d_ws, size_t ws_size,
                              hipStream_t stream){
    const float* x     = (const float*)d_in[0];
    const int*   ei    = (const int*)  d_in[1];
    const float* W1    = (const float*)d_in[2];
    const float* asrc1 = (const float*)d_in[3];
    const float* adst1 = (const float*)d_in[4];
    const float* b1    = (const float*)d_in[5];
    const float* W2    = (const float*)d_in[6];
    const float* asrc2 = (const float*)d_in[7];
    const float* adst2 = (const float*)d_in[8];
    const float* b2    = (const float*)d_in[9];
    float* out = (float*)d_out;

    const int N = in_sizes[0] / IN_CH;   // 100000
    const int E = in_sizes[1] / 2;       // 1600000
    const int ETOT = E + N;
    const int NBUCK = (N + NPB - 1) / NPB;   // 391

    char* p = (char*)d_ws;
    auto alloc = [&](size_t bytes) -> char* {
        char* r = p; p += (bytes + 255) & ~(size_t)255; return r;
    };
    __half2* h1h  = (__half2*)alloc((size_t)N * 64 * 4);
    __half2* hl2h = (__half2*)alloc((size_t)N * 64 * 4);
    float* as1   = (float*)alloc((size_t)N * 8 * 4);
    float* ad1   = (float*)alloc((size_t)N * 8 * 4);
    float* h2    = (float*)alloc((size_t)N * 16 * 4);
    float* as2   = (float*)alloc((size_t)N * 4);
    float* ad2   = (float*)alloc((size_t)N * 4);
    int*   bcnt  = (int*)  alloc((size_t)MAXBUCK * 4);
    int*   boffs = (int*)  alloc((size_t)(MAXBUCK + 1) * 4);
    int*   bcur  = (int*)  alloc((size_t)MAXBUCK * 4);
    int*   offs  = (int*)  alloc((size_t)(N + 1) * 4);
    int*   esrc  = (int*)  alloc((size_t)ETOT * 4);
    int2*  ebuck = (int2*)hl2h;   // aliases hl2h; k_csr done before k_agg1 writes it

    hipMemsetAsync(bcnt, 0, (size_t)NBUCK * 4, stream);

    const int GPART = 512;
    const int epb = (E + GPART - 1) / GPART;

    k_bhist   <<<GPART, 256, 0, stream>>>(ei + E, E, NBUCK, epb, bcnt);
    k_bscan   <<<1,     512, 0, stream>>>(bcnt, NBUCK, E, boffs, bcur);
    k_bscatter<<<GPART, 256, 0, stream>>>(ei, E, NBUCK, epb, bcur, ebuck);
    k_csr     <<<NBUCK, 256, 0, stream>>>(ebuck, boffs, N, E, offs, esrc);

    k_gemm1  <<<(N + 63) / 64, 256, 0, stream>>>(x, W1, (__half*)h1h, N);
    k_alpha1 <<<(N * HEADS + 255) / 256, 256, 0, stream>>>(h1h, asrc1, adst1, as1, ad1, N);
    k_agg1   <<<(N + 3) / 4, 256, 0, stream>>>(h1h, as1, ad1, offs, esrc, b1, hl2h, N);
    k_gemm2  <<<(N + 63) / 64, 256, 0, stream>>>(hl2h, W2, asrc2, adst2, h2, as2, ad2, N);
    k_agg2   <<<(N + 3) / 4, 256, 0, stream>>>(h2, as2, ad2, offs, esrc, b2, out, N);
}

// Round 11
// 350.515 us; speedup vs baseline: 1.0953x; 1.0953x over previous
//
#include <hip/hip_runtime.h>
#include <hip/hip_fp16.h>
#include <math.h>

#define IN_CH 128
#define HEADS 8
#define HID 16
#define OUT_CH 16
#define NEG 0.2f
#define NPB 256          // nodes per bucket (>>8)
#define MAXBUCK 400
#define AST 136          // LDS k-stride in halfs (128 + 8 pad)

__device__ __forceinline__ float lrelu(float x){ return x > 0.f ? x : NEG * x; }

typedef _Float16 half8 __attribute__((ext_vector_type(8)));
typedef float    f32x4 __attribute__((ext_vector_type(4)));

// ---------------- bucketed CSR build ----------------
__global__ __launch_bounds__(256) void k_bhist(const int* __restrict__ tgt, int E, int nbuck, int epb,
                                               int* __restrict__ bcnt){
    __shared__ int hist[MAXBUCK];
    int tid = threadIdx.x;
    for (int i = tid; i < nbuck; i += 256) hist[i] = 0;
    __syncthreads();
    int start = blockIdx.x * epb, end = min(start + epb, E);
    for (int e = start + tid; e < end; e += 256) atomicAdd(&hist[tgt[e] >> 8], 1);
    __syncthreads();
    for (int i = tid; i < nbuck; i += 256) if (hist[i]) atomicAdd(&bcnt[i], hist[i]);
}

__global__ void k_bscan(const int* __restrict__ bcnt, int nbuck, int E,
                        int* __restrict__ boffs, int* __restrict__ bcur){
    __shared__ int s[512];
    int t = threadIdx.x;
    int v = (t < nbuck) ? bcnt[t] : 0;
    int orig = v;
    s[t] = v; __syncthreads();
    for (int off = 1; off < 512; off <<= 1){
        int u = (t >= off) ? s[t - off] : 0;
        __syncthreads();
        v += u; s[t] = v; __syncthreads();
    }
    if (t < nbuck){ boffs[t] = v - orig; bcur[t] = v - orig; }
    if (t == 0) boffs[nbuck] = E;
}

__global__ __launch_bounds__(256) void k_bscatter(const int* __restrict__ ei, int E, int nbuck, int epb,
                                                  int* __restrict__ bcur, int2* __restrict__ ebuck){
    __shared__ int hist[MAXBUCK];
    __shared__ int base[MAXBUCK];
    int tid = threadIdx.x;
    for (int i = tid; i < nbuck; i += 256) hist[i] = 0;
    __syncthreads();
    int start = blockIdx.x * epb, end = min(start + epb, E);
    for (int e = start + tid; e < end; e += 256) atomicAdd(&hist[ei[E + e] >> 8], 1);
    __syncthreads();
    for (int i = tid; i < nbuck; i += 256){
        base[i] = hist[i] ? atomicAdd(&bcur[i], hist[i]) : 0;
        hist[i] = 0;
    }
    __syncthreads();
    for (int e = start + tid; e < end; e += 256){
        int s = ei[e], t = ei[E + e];
        int b = t >> 8;
        int r = atomicAdd(&hist[b], 1);
        ebuck[base[b] + r] = make_int2(s, t);
    }
}

__global__ __launch_bounds__(256) void k_csr(const int2* __restrict__ ebuck, const int* __restrict__ boffs,
                                             int N, int E,
                                             int* __restrict__ offs, int* __restrict__ esrc){
    __shared__ int cnt[256];
    __shared__ int sscan[256];
    __shared__ int wcur[256];
    int b = blockIdx.x;
    int tid = threadIdx.x;
    int n0 = b * 256;
    int nn = min(256, N - n0);
    cnt[tid] = (tid < nn) ? 1 : 0;
    __syncthreads();
    int e0 = boffs[b], e1 = boffs[b + 1];
    for (int e = e0 + tid; e < e1; e += 256) atomicAdd(&cnt[ebuck[e].y & 255], 1);
    __syncthreads();
    int v = cnt[tid], orig = v;
    sscan[tid] = v; __syncthreads();
    for (int off = 1; off < 256; off <<= 1){
        int u = (tid >= off) ? sscan[tid - off] : 0;
        __syncthreads();
        v += u; sscan[tid] = v; __syncthreads();
    }
    int excl = v - orig;
    int gbase = e0 + n0;
    if (tid < nn){
        offs[n0 + tid] = gbase + excl;
        esrc[gbase + excl] = n0 + tid;
    }
    wcur[tid] = excl + 1;
    __syncthreads();
    for (int e = e0 + tid; e < e1; e += 256){
        int2 p = ebuck[e];
        int r = atomicAdd(&wcur[p.y & 255], 1);
        esrc[gbase + r] = p.x;
    }
    if (b == 0 && tid == 0) offs[N] = E + N;
}

// ---------------- GEMM1 (MFMA fp16): h1 = x @ W1 -> fp16 [N][128] ----------------
__global__ __launch_bounds__(256) void k_gemm1(const float* __restrict__ x, const float* __restrict__ W1,
                                               __half* __restrict__ h1, int N){
    __shared__ _Float16 sA[64*AST];    // 17.4 KB
    __shared__ _Float16 sB[128*AST];   // 34.8 KB
    int tid = threadIdx.x;
    for (int i = tid; i < 128*128; i += 256){
        int k = i >> 7, c = i & 127;
        sB[c*AST + k] = (_Float16)W1[i];
    }
    int row0 = blockIdx.x * 64;
    #pragma unroll
    for (int i = 0; i < 8; ++i){
        int q = i*256 + tid;
        int r = q >> 5, seg = q & 31;
        float4 v = make_float4(0.f,0.f,0.f,0.f);
        if (row0 + r < N) v = *(const float4*)(x + (size_t)(row0+r)*128 + seg*4);
        _Float16* dst = &sA[r*AST + seg*4];
        dst[0]=(_Float16)v.x; dst[1]=(_Float16)v.y; dst[2]=(_Float16)v.z; dst[3]=(_Float16)v.w;
    }
    __syncthreads();
    int wave = tid >> 6, lane = tid & 63;
    int m = lane & 15, quad = lane >> 4;
    int rbase = wave * 16;
    f32x4 acc[8] = {};
    #pragma unroll
    for (int kc = 0; kc < 4; ++kc){
        int kb = kc*32 + quad*8;
        half8 a = *(half8*)(&sA[(rbase + m)*AST + kb]);
        #pragma unroll
        for (int t = 0; t < 8; ++t){
            half8 b = *(half8*)(&sB[(t*16 + m)*AST + kb]);
            acc[t] = __builtin_amdgcn_mfma_f32_16x16x32_f16(a, b, acc[t], 0, 0, 0);
        }
    }
    #pragma unroll
    for (int t = 0; t < 8; ++t){
        #pragma unroll
        for (int j = 0; j < 4; ++j){
            int r = row0 + rbase + quad*4 + j;
            if (r < N) h1[(size_t)r*128 + t*16 + m] = __float2half(acc[t][j]);
        }
    }
}

// ---------------- attention logits, layer 1 ----------------
struct H8 { __half2 v[8]; };

__global__ void k_alpha1(const __half2* __restrict__ h1h, const float* __restrict__ asrc, const float* __restrict__ adst,
                         float* __restrict__ as1, float* __restrict__ ad1, int N){
    int idx = blockIdx.x*blockDim.x + threadIdx.x;
    if (idx >= N*HEADS) return;
    int h = idx & 7;
    int n = idx >> 3;
    H8 blk = *(const H8*)(h1h + (size_t)n*64 + h*8);
    const float2* sp = (const float2*)(asrc + h*16);
    const float2* dp = (const float2*)(adst + h*16);
    float ss = 0.f, dd = 0.f;
    #pragma unroll
    for (int j = 0; j < 8; ++j){
        float2 v = __half22float2(blk.v[j]);
        float2 a = sp[j], b = dp[j];
        ss += v.x*a.x + v.y*a.y;
        dd += v.x*b.x + v.y*b.y;
    }
    as1[idx] = ss; ad1[idx] = dd;
}

// ---------------- layer-1 aggregation: 2 nodes/wave, 4 ch/lane, shift-free ----------------
// wave wv handles nodes 2wv,2wv+1 of its block-pair; sub = lane>>5 picks the node,
// ll = lane&31 owns channels 4ll..4ll+3 (head = ll>>2). Per wave-instruction two
// edges (one per sub) are processed -> per-edge issue cost ~halves vs 64-lane/node.
// Tail/imbalance slots use w=0 + clamped index (exact no-op).
__global__ __launch_bounds__(256) void k_agg1(const __half2* __restrict__ h1h, const float* __restrict__ as1,
                                              const float* __restrict__ ad1,
                                              const int* __restrict__ offs, const int* __restrict__ esrc,
                                              const float* __restrict__ b1, __half2* __restrict__ hl2h, int N){
    int wv = threadIdx.x >> 6;
    int l  = threadIdx.x & 63;
    int sub = l >> 5, ll = l & 31;
    int n = blockIdx.x*8 + wv*2 + sub;
    bool alive = (n < N);
    int h = ll >> 2;
    float adh = 0.f;
    int e0 = 0, deg = 0;
    if (alive){
        adh = ad1[n*8 + h];
        e0 = offs[n];
        deg = offs[n+1] - e0;
    }
    int degmax = max(deg, __shfl_xor(deg, 32));

    float4 acc0 = make_float4(0.f,0.f,0.f,0.f), acc1 = make_float4(0.f,0.f,0.f,0.f);
    float den0 = 0.f, den1 = 0.f;
    for (int i = 0; i < degmax; i += 2){
        bool v0 = i < deg, v1 = (i+1) < deg;
        int i0 = e0 + (v0 ? i   : 0);
        int i1 = e0 + (v1 ? i+1 : 0);
        int s0 = esrc[i0], s1 = esrc[i1];
        float a0 = as1[s0*8 + h], a1 = as1[s1*8 + h];
        float2 p0 = *(const float2*)(h1h + (size_t)s0*64 + ll*2);   // 2 half2 = 4 ch
        float2 p1 = *(const float2*)(h1h + (size_t)s1*64 + ll*2);
        float w0 = v0 ? __expf(lrelu(a0 + adh)) : 0.f;
        float w1 = v1 ? __expf(lrelu(a1 + adh)) : 0.f;
        float2 f0a = __half22float2(*(__half2*)&p0.x), f0b = __half22float2(*(__half2*)&p0.y);
        float2 f1a = __half22float2(*(__half2*)&p1.x), f1b = __half22float2(*(__half2*)&p1.y);
        den0 += w0; den1 += w1;
        acc0.x += w0*f0a.x; acc0.y += w0*f0a.y; acc0.z += w0*f0b.x; acc0.w += w0*f0b.y;
        acc1.x += w1*f1a.x; acc1.y += w1*f1a.y; acc1.z += w1*f1b.x; acc1.w += w1*f1b.y;
    }
    if (!alive) return;
    float rd = 1.f / (den0 + den1 + 1e-16f);
    float4 bb = *(const float4*)(b1 + ll*4);
    float o0 = (acc0.x + acc1.x)*rd + bb.x;
    float o1 = (acc0.y + acc1.y)*rd + bb.y;
    float o2 = (acc0.z + acc1.z)*rd + bb.z;
    float o3 = (acc0.w + acc1.w)*rd + bb.w;
    o0 = o0 > 0.f ? o0 : expm1f(o0);
    o1 = o1 > 0.f ? o1 : expm1f(o1);
    o2 = o2 > 0.f ? o2 : expm1f(o2);
    o3 = o3 > 0.f ? o3 : expm1f(o3);
    __half2 q0 = __floats2half2_rn(o0, o1);
    __half2 q1 = __floats2half2_rn(o2, o3);
    float2 ov;
    *(__half2*)&ov.x = q0; *(__half2*)&ov.y = q1;
    *(float2*)(hl2h + (size_t)n*64 + ll*2) = ov;
}

// ---------------- GEMM2: h2 = hl2 @ W2 -> fp16 + fused alpha2 ----------------
#define FMA4(acc, a, b) { acc.x += (a)*(b).x; acc.y += (a)*(b).y; acc.z += (a)*(b).z; acc.w += (a)*(b).w; }

__global__ __launch_bounds__(256) void k_gemm2(const __half2* __restrict__ hl2h, const float* __restrict__ W2,
                                               const float* __restrict__ asrc2, const float* __restrict__ adst2,
                                               __half2* __restrict__ h2h, float* __restrict__ as2, float* __restrict__ ad2,
                                               int N){
    __shared__ float sX[64*132];
    __shared__ float sW2[128*16];
    int tid = threadIdx.x;
    for (int i = tid; i < 128*16; i += 256) sW2[i] = W2[i];
    int row0 = blockIdx.x * 64;
    #pragma unroll
    for (int i = 0; i < 4; ++i){
        int q = i*256 + tid;
        int r = q >> 4, seg = q & 15;
        float4 raw = make_float4(0.f,0.f,0.f,0.f);
        if (row0 + r < N) raw = ((const float4*)(hl2h + (size_t)(row0+r)*64))[seg];
        const __half2* hp = (const __half2*)&raw;
        float* dst = &sX[r*132 + seg*8];
        #pragma unroll
        for (int j = 0; j < 4; ++j){
            float2 f = __half22float2(hp[j]);
            dst[2*j] = f.x; dst[2*j+1] = f.y;
        }
    }
    __syncthreads();
    int nd = tid >> 2;
    int cq = tid & 3, c0 = cq*4;
    int n = row0 + nd;
    float4 acc = make_float4(0.f,0.f,0.f,0.f);
    #pragma unroll 4
    for (int k4 = 0; k4 < 32; ++k4){
        float4 a  = *(const float4*)(&sX[nd*132 + k4*4]);
        float4 w0 = *(const float4*)(&sW2[(k4*4+0)*16 + c0]);
        float4 w1 = *(const float4*)(&sW2[(k4*4+1)*16 + c0]);
        float4 w2 = *(const float4*)(&sW2[(k4*4+2)*16 + c0]);
        float4 w3 = *(const float4*)(&sW2[(k4*4+3)*16 + c0]);
        FMA4(acc, a.x, w0); FMA4(acc, a.y, w1); FMA4(acc, a.z, w2); FMA4(acc, a.w, w3);
    }
    float ps = acc.x*asrc2[c0] + acc.y*asrc2[c0+1] + acc.z*asrc2[c0+2] + acc.w*asrc2[c0+3];
    float pd = acc.x*adst2[c0] + acc.y*adst2[c0+1] + acc.z*adst2[c0+2] + acc.w*adst2[c0+3];
    ps += __shfl_xor(ps, 1); ps += __shfl_xor(ps, 2);
    pd += __shfl_xor(pd, 1); pd += __shfl_xor(pd, 2);
    if (n < N){
        __half2 p0 = __floats2half2_rn(acc.x, acc.y);
        __half2 p1 = __floats2half2_rn(acc.z, acc.w);
        float2 ov;
        *(__half2*)&ov.x = p0; *(__half2*)&ov.y = p1;
        *(float2*)(h2h + (size_t)n*8 + cq*2) = ov;
        if (cq == 0){ as2[n] = ps; ad2[n] = pd; }
    }
}

// ---------------- layer-2 fused aggregation (fp16 h2 gather) -> out ----------------
__global__ __launch_bounds__(256) void k_agg2(const __half* __restrict__ h2x, const float* __restrict__ as2v,
                                              const float* __restrict__ ad2v,
                                              const int* __restrict__ offs, const int* __restrict__ esrc,
                                              const float* __restrict__ b2, float* __restrict__ out, int N){
    int n = blockIdx.x*4 + (threadIdx.x >> 6);
    if (n >= N) return;
    int l = threadIdx.x & 63;
    int e0 = offs[n], e1 = offs[n+1];
    float ad = ad2v[n];
    int eo = l >> 4, c = l & 15;
    float acc = 0.f, den = 0.f;
    for (int e = e0 + eo; e < e1; e += 4){
        int s = esrc[e];
        float w = __expf(lrelu(as2v[s] + ad));
        den += w;
        acc += w * __half2float(h2x[(size_t)s*16 + c]);
    }
    acc += __shfl_xor(acc, 16); den += __shfl_xor(den, 16);
    acc += __shfl_xor(acc, 32); den += __shfl_xor(den, 32);
    if (eo == 0) out[(size_t)n*16 + c] = acc / (den + 1e-16f) + b2[c];
}

extern "C" void kernel_launch(void* const* d_in, const int* in_sizes, int n_in,
                              void* d_out, int out_size, void* d_ws, size_t ws_size,
                              hipStream_t stream){
    const float* x     = (const float*)d_in[0];
    const int*   ei    = (const int*)  d_in[1];
    const float* W1    = (const float*)d_in[2];
    const float* asrc1 = (const float*)d_in[3];
    const float* adst1 = (const float*)d_in[4];
    const float* b1    = (const float*)d_in[5];
    const float* W2    = (const float*)d_in[6];
    const float* asrc2 = (const float*)d_in[7];
    const float* adst2 = (const float*)d_in[8];
    const float* b2    = (const float*)d_in[9];
    float* out = (float*)d_out;

    const int N = in_sizes[0] / IN_CH;   // 100000
    const int E = in_sizes[1] / 2;       // 1600000
    const int ETOT = E + N;
    const int NBUCK = (N + NPB - 1) / NPB;   // 391

    char* p = (char*)d_ws;
    auto alloc = [&](size_t bytes) -> char* {
        char* r = p; p += (bytes + 255) & ~(size_t)255; return r;
    };
    __half2* h1h  = (__half2*)alloc((size_t)N * 64 * 4);
    __half2* hl2h = (__half2*)alloc((size_t)N * 64 * 4);
    float* as1   = (float*)alloc((size_t)N * 8 * 4);
    float* ad1   = (float*)alloc((size_t)N * 8 * 4);
    __half2* h2h = (__half2*)alloc((size_t)N * 8 * 4);
    float* as2   = (float*)alloc((size_t)N * 4);
    float* ad2   = (float*)alloc((size_t)N * 4);
    int*   bcnt  = (int*)  alloc((size_t)MAXBUCK * 4);
    int*   boffs = (int*)  alloc((size_t)(MAXBUCK + 1) * 4);
    int*   bcur  = (int*)  alloc((size_t)MAXBUCK * 4);
    int*   offs  = (int*)  alloc((size_t)(N + 1) * 4);
    int*   esrc  = (int*)  alloc((size_t)ETOT * 4);
    int2*  ebuck = (int2*)hl2h;   // aliases hl2h; k_csr done before k_agg1 writes it

    hipMemsetAsync(bcnt, 0, (size_t)NBUCK * 4, stream);

    const int GPART = 512;
    const int epb = (E + GPART - 1) / GPART;

    k_bhist   <<<GPART, 256, 0, stream>>>(ei + E, E, NBUCK, epb, bcnt);
    k_bscan   <<<1,     512, 0, stream>>>(bcnt, NBUCK, E, boffs, bcur);
    k_bscatter<<<GPART, 256, 0, stream>>>(ei, E, NBUCK, epb, bcur, ebuck);
    k_csr     <<<NBUCK, 256, 0, stream>>>(ebuck, boffs, N, E, offs, esrc);

    k_gemm1  <<<(N + 63) / 64, 256, 0, stream>>>(x, W1, (__half*)h1h, N);
    k_alpha1 <<<(N * HEADS + 255) / 256, 256, 0, stream>>>(h1h, asrc1, adst1, as1, ad1, N);
    k_agg1   <<<(N + 7) / 8, 256, 0, stream>>>(h1h, as1, ad1, offs, esrc, b1, hl2h, N);
    k_gemm2  <<<(N + 63) / 64, 256, 0, stream>>>(hl2h, W2, asrc2, adst2, h2h, as2, ad2, N);
    k_agg2   <<<(N + 3) / 4, 256, 0, stream>>>((const __half*)h2h, as2, ad2, offs, esrc, b2, out, N);
}